// Round 2
// 160.228 us; speedup vs baseline: 1.0394x; 1.0394x over previous
//
#include <hip/hip_runtime.h>

#define NNODE 16384
#define DD 32
#define INPC 256
#define UC 128
#define RC 8
#define EC 8

typedef __attribute__((ext_vector_type(8))) short short8;
typedef __attribute__((ext_vector_type(4))) float float4v;
typedef __attribute__((ext_vector_type(4))) unsigned uint4v;

__device__ __forceinline__ unsigned short f2bf(float f) {
    unsigned u = __builtin_bit_cast(unsigned, f);
    unsigned r = (u + 0x7FFFu + ((u >> 16) & 1u)) >> 16;   // RNE
    return (unsigned short)r;
}
__device__ __forceinline__ float bf2f(unsigned short s) { return __builtin_bit_cast(float, (unsigned)s << 16); }

// load 8 consecutive fp32 and convert to a bf16 MFMA fragment half
__device__ __forceinline__ short8 ld8bf(const float* p) {
    float4 v0 = *(const float4*)p;
    float4 v1 = *(const float4*)(p + 4);
    short8 a;
    a[0] = (short)f2bf(v0.x); a[1] = (short)f2bf(v0.y);
    a[2] = (short)f2bf(v0.z); a[3] = (short)f2bf(v0.w);
    a[4] = (short)f2bf(v1.x); a[5] = (short)f2bf(v1.y);
    a[6] = (short)f2bf(v1.z); a[7] = (short)f2bf(v1.w);
    return a;
}

// B-fragment flat index for mfma_f32_16x16x32_bf16. nct = #16-col tiles.
__device__ __forceinline__ int bfrag_idx(int k, int col, int nct) {
    int ks = k >> 5, ct = col >> 4;
    int l = (((k >> 3) & 3) << 4) | (col & 15);
    return (((ks * nct + ct) << 6) + l) * 8 + (k & 7);
}

// ---------- setup: [0,1024) pew->frag | [1024,1088) prep (MFMA) | [1088,1152) hist ----------
__global__ void k_setup(const float* __restrict__ pew, const float* __restrict__ qw,
                        const float* __restrict__ kw, const float* __restrict__ relw,
                        const float* __restrict__ vw, const float* __restrict__ fcw,
                        const int* __restrict__ pe,
                        unsigned short* __restrict__ pewfrag,
                        unsigned short* __restrict__ BallQfrag, unsigned short* __restrict__ RVFfrag,
                        int* __restrict__ blockhist) {
    __shared__ unsigned short stage_s[128 * 132];   // ~33.8 KB: vw then fcw (bf16)
    __shared__ unsigned short mat_s[16 * 136];      // ~4.35 KB: P then RV (bf16)
    __shared__ int hh[8];
    int b = blockIdx.x;
    if (b < 1024) {                   // pew -> B-fragments (K=256, N=128 per entity)
        int id = b * 256 + threadIdx.x;
        int e = id >> 15, k = (id >> 7) & 255, col = id & 127;
        pewfrag[(e << 15) + bfrag_idx(k, col, 8)] = f2bf(pew[id]);
        return;
    }
    if (b < 1088) {                   // prep: all four small GEMMs via MFMA
        int pb = b - 1024;
        int r = pb & 7, i0 = (pb >> 3) * 16;
        int w = threadIdx.x >> 6, l = threadIdx.x & 63;
        int mrow = l & 15, kgrp = (l >> 4) << 3;
        const float* R = relw + r * (UC * UC);

        // ---- phase P: P rows i0..i0+16 = qw[i0..] @ kw^T
        float4v accP[2] = {};
        #pragma unroll
        for (int ks = 0; ks < 4; ++ks) {
            short8 a = ld8bf(&qw[(i0 + mrow) * UC + ks * 32 + kgrp]);
            #pragma unroll
            for (int ci = 0; ci < 2; ++ci) {
                int ct = w * 2 + ci;
                short8 bf = ld8bf(&kw[(ct * 16 + mrow) * UC + ks * 32 + kgrp]);
                accP[ci] = __builtin_amdgcn_mfma_f32_16x16x32_bf16(a, bf, accP[ci], 0, 0, 0);
            }
        }
        #pragma unroll
        for (int ci = 0; ci < 2; ++ci)
            #pragma unroll
            for (int reg = 0; reg < 4; ++reg) {
                int row = ((l >> 4) << 2) + reg;
                int col = (w * 2 + ci) * 16 + mrow;
                mat_s[row * 136 + col] = f2bf(accP[ci][reg] * (1.0f / 128.0f));
            }
        // stage vw (bf16, stride 132)
        for (int it = 0; it < 16; ++it) {
            int idx = it * 256 + threadIdx.x;      // float4 index
            int row = idx >> 5, col = (idx & 31) * 4;
            float4 v = *(const float4*)&vw[row * UC + col];
            uint2 o;
            o.x = (unsigned)f2bf(v.x) | ((unsigned)f2bf(v.y) << 16);
            o.y = (unsigned)f2bf(v.z) | ((unsigned)f2bf(v.w) << 16);
            *(uint2*)&stage_s[row * 132 + col] = o;
        }
        __syncthreads();

        // ---- phase M: M = P @ R^T ; phase RV: RV = R @ vw (interleaved)
        float4v accM[2] = {}, accV[2] = {};
        #pragma unroll
        for (int ks = 0; ks < 4; ++ks) {
            short8 aM = *(const short8*)&mat_s[mrow * 136 + ks * 32 + kgrp];
            short8 aV = ld8bf(&R[(i0 + mrow) * UC + ks * 32 + kgrp]);
            #pragma unroll
            for (int ci = 0; ci < 2; ++ci) {
                int ct = w * 2 + ci;
                short8 bM = ld8bf(&R[(ct * 16 + mrow) * UC + ks * 32 + kgrp]);
                accM[ci] = __builtin_amdgcn_mfma_f32_16x16x32_bf16(aM, bM, accM[ci], 0, 0, 0);
                uint4v pv;
                #pragma unroll
                for (int jp = 0; jp < 4; ++jp) {
                    unsigned e0 = stage_s[(ks * 32 + kgrp + jp * 2) * 132 + ct * 16 + mrow];
                    unsigned e1 = stage_s[(ks * 32 + kgrp + jp * 2 + 1) * 132 + ct * 16 + mrow];
                    pv[jp] = e0 | (e1 << 16);
                }
                accV[ci] = __builtin_amdgcn_mfma_f32_16x16x32_bf16(
                    aV, __builtin_bit_cast(short8, pv), accV[ci], 0, 0, 0);
            }
        }
        #pragma unroll
        for (int ci = 0; ci < 2; ++ci)
            #pragma unroll
            for (int reg = 0; reg < 4; ++reg) {
                int i = i0 + ((l >> 4) << 2) + reg;
                int col = r * 128 + (w * 2 + ci) * 16 + mrow;
                BallQfrag[bfrag_idx(i, col, 64)] = f2bf(accM[ci][reg]);
            }
        __syncthreads();   // mat_s / stage_s reads done
        // store RV rows; stage fcw
        #pragma unroll
        for (int ci = 0; ci < 2; ++ci)
            #pragma unroll
            for (int reg = 0; reg < 4; ++reg)
                mat_s[(((l >> 4) << 2) + reg) * 136 + (w * 2 + ci) * 16 + mrow] = f2bf(accV[ci][reg]);
        for (int it = 0; it < 16; ++it) {
            int idx = it * 256 + threadIdx.x;
            int row = idx >> 5, col = (idx & 31) * 4;
            float4 v = *(const float4*)&fcw[row * UC + col];
            uint2 o;
            o.x = (unsigned)f2bf(v.x) | ((unsigned)f2bf(v.y) << 16);
            o.y = (unsigned)f2bf(v.z) | ((unsigned)f2bf(v.w) << 16);
            *(uint2*)&stage_s[row * 132 + col] = o;
        }
        __syncthreads();

        // ---- phase RVF: RVF = RV @ fcw
        float4v accF[2] = {};
        #pragma unroll
        for (int ks = 0; ks < 4; ++ks) {
            short8 aF = *(const short8*)&mat_s[mrow * 136 + ks * 32 + kgrp];
            #pragma unroll
            for (int ci = 0; ci < 2; ++ci) {
                int ct = w * 2 + ci;
                uint4v pv;
                #pragma unroll
                for (int jp = 0; jp < 4; ++jp) {
                    unsigned e0 = stage_s[(ks * 32 + kgrp + jp * 2) * 132 + ct * 16 + mrow];
                    unsigned e1 = stage_s[(ks * 32 + kgrp + jp * 2 + 1) * 132 + ct * 16 + mrow];
                    pv[jp] = e0 | (e1 << 16);
                }
                accF[ci] = __builtin_amdgcn_mfma_f32_16x16x32_bf16(
                    aF, __builtin_bit_cast(short8, pv), accF[ci], 0, 0, 0);
            }
        }
        #pragma unroll
        for (int ci = 0; ci < 2; ++ci)
            #pragma unroll
            for (int reg = 0; reg < 4; ++reg) {
                int i = i0 + ((l >> 4) << 2) + reg;
                int col = (w * 2 + ci) * 16 + mrow;
                RVFfrag[bfrag_idx(r * 128 + i, col, 8)] = f2bf(accF[ci][reg]);
            }
        return;
    }
    {   // hist
        int hb = b - 1088;
        if (threadIdx.x < 8) hh[threadIdx.x] = 0;
        __syncthreads();
        atomicAdd(&hh[pe[hb * 256 + threadIdx.x]], 1);
        __syncthreads();
        if (threadIdx.x < 8) blockhist[hb * 8 + threadIdx.x] = hh[threadIdx.x];
    }
}

// ---------- scatter: wave-parallel scan + ballot rank (no global atomics) ----------
__global__ void k_scatter(const int* __restrict__ pe, const int* __restrict__ blockhist,
                          int* __restrict__ list, int* __restrict__ cnt, int* __restrict__ basep) {
    __shared__ int boff[8];
    __shared__ int totS[8], exS[8];
    __shared__ int wavecnt[4 * 8];
    int t = threadIdx.x, w = t >> 6, l = t & 63;
    if (w == 0) {
        #pragma unroll
        for (int e = 0; e < 8; ++e) {
            int h = blockhist[l * 8 + e];
            int pref = h;
            #pragma unroll
            for (int off = 1; off < 64; off <<= 1) {
                int v = __shfl_up(pref, off, 64);
                pref += (l >= off) ? v : 0;
            }
            if (l == (int)blockIdx.x) exS[e] = pref - h;
            if (l == 63) totS[e] = pref;
        }
    }
    __syncthreads();
    if (t == 0) {
        int run = 0;
        #pragma unroll
        for (int e = 0; e < 8; ++e) {
            boff[e] = run + exS[e];
            if (blockIdx.x == 0) { basep[e] = run; cnt[e] = totS[e]; }
            run += totS[e];
        }
    }
    __syncthreads();
    int n = blockIdx.x * 256 + t;
    int e = pe[n];
    unsigned long long mymask = 0;
    #pragma unroll
    for (int r = 0; r < 8; ++r) {
        unsigned long long m = __ballot(e == r);
        if (e == r) mymask = m;
        if (l == r) wavecnt[w * 8 + r] = (int)__popcll(m);
    }
    __syncthreads();
    int off = 0;
    for (int w2 = 0; w2 < w; ++w2) off += wavecnt[w2 * 8 + e];
    unsigned long long ltmask = (1ull << l) - 1ull;
    int rank = (int)__popcll(mymask & ltmask);
    list[boff[e] + off + rank] = n;
}

// ---------- center (MFMA): reads fp32 ns directly, converts in-register ----------
__global__ __launch_bounds__(256, 4)
void k_center(const float* __restrict__ ns, const unsigned short* __restrict__ pewfrag,
              const int* __restrict__ list, const int* __restrict__ cnt,
              const int* __restrict__ base, unsigned short* __restrict__ center_bf) {
    int e = blockIdx.y;
    int c = cnt[e];
    int start = blockIdx.x * 16;
    if (start >= c) return;
    int w = threadIdx.x >> 6, l = threadIdx.x & 63;

    int rid = list[base[e] + min(start + (l & 15), c - 1)];

    float4v acc[2] = {};
    const unsigned short* pf = pewfrag + ((size_t)e << 15);
    #pragma unroll
    for (int ks = 0; ks < 8; ++ks) {
        short8 a = ld8bf(&ns[(size_t)rid * 256 + ks * 32 + ((l >> 4) << 3)]);
        #pragma unroll
        for (int ci = 0; ci < 2; ++ci) {
            int ct = w * 2 + ci;
            short8 b = *(const short8*)&pf[(((ks * 8 + ct) << 6) + l) * 8];
            acc[ci] = __builtin_amdgcn_mfma_f32_16x16x32_bf16(a, b, acc[ci], 0, 0, 0);
        }
    }
    #pragma unroll
    for (int reg = 0; reg < 4; ++reg) {
        int row16 = start + ((l >> 4) << 2) + reg;
        if (row16 < c) {
            int gid = list[base[e] + row16];
            #pragma unroll
            for (int ci = 0; ci < 2; ++ci)
                center_bf[(size_t)gid * 128 + (w * 2 + ci) * 16 + (l & 15)] = f2bf(acc[ci][reg]);
        }
    }
}

// ---------- final: qr MFMA->LDS + LDS-staged phase B (scores MFMA + softmax +
//            bucket MFMA from staged LDS) + bucket@RVF MFMA + epilogue ----------
// Phase-B X staging layout (per wave, 32 edges x 128 ch bf16, 8 KB), XOR-swizzled:
//   elem_off(edge, ch) = (ch>>4)*512 + (edge>>2)*64 + slot*16 + (ch&15)
//   where slot = (edge&3) ^ ((edge>>2)&3)
// The swizzle spreads fixed-channel cross-edge gathers (bucket path) from an
// 8-way to a ~4-way bank pattern while keeping all writes/reads 16B-contiguous.
#define QSTRIDE 1096
__global__ __launch_bounds__(256, 2)
void k_final(const unsigned short* __restrict__ center_bf,
             const unsigned short* __restrict__ BallQfrag,
             const unsigned short* __restrict__ RVFfrag,
             const int* __restrict__ adj, const int* __restrict__ rel,
             const float* __restrict__ fcb, float* __restrict__ out) {
    __shared__ unsigned short qlds[16 * QSTRIDE];            // ~35 KB
    __shared__ __align__(16) unsigned short xs[4][4096];     // 32 KB: per-wave X staging
    __shared__ unsigned edata[4][32];                        // per-wave edge metadata
    int w = threadIdx.x >> 6, l = threadIdx.x & 63;
    int n0 = blockIdx.x * 16;

    // ---- preload adjacency/relations for this wave's 4 nodes
    int aiq[4][2], rvq[4][2], myrow[4];
    #pragma unroll
    for (int q = 0; q < 4; ++q) {
        int n = n0 + w * 4 + q;
        #pragma unroll
        for (int t = 0; t < 2; ++t) {
            aiq[q][t] = adj[n * DD + t * 16 + (l & 15)];
            rvq[q][t] = rel[n * DD + t * 16 + (l & 15)];
        }
    }
    // staging lane l covers edge e(l) = (l>>5)*16 + ((l>>1)&15), chunks c = (l&1) + 2i
    #pragma unroll
    for (int q = 0; q < 4; ++q) {
        int r0 = aiq[q][0] > 0 ? aiq[q][0] - 1 : 0;
        int r1 = aiq[q][1] > 0 ? aiq[q][1] - 1 : 0;
        int s0 = __shfl(r0, (l >> 1) & 15, 64);
        int s1 = __shfl(r1, (l >> 1) & 15, 64);
        myrow[q] = (l >= 32) ? s1 : s0;
    }
    // issue q=0's X loads now; they land under phase A
    uint4v sb[8];
    #pragma unroll
    for (int i = 0; i < 8; ++i)
        sb[i] = *(const uint4v*)&center_bf[(size_t)myrow[0] * 128 + ((l & 1) + 2 * i) * 8];

    // phase A: qr tile (16 nodes x 1024) into LDS; wave w computes cols w*256..+256
    {
        short8 a[4];
        #pragma unroll
        for (int ks = 0; ks < 4; ++ks)
            a[ks] = *(const short8*)&center_bf[(size_t)(n0 + (l & 15)) * 128 + ks * 32 + ((l >> 4) << 3)];
        for (int ci = 0; ci < 16; ++ci) {
            int ct = w * 16 + ci;
            float4v acc = {};
            #pragma unroll
            for (int ks = 0; ks < 4; ++ks) {
                short8 b = *(const short8*)&BallQfrag[(((ks * 64 + ct) << 6) + l) * 8];
                acc = __builtin_amdgcn_mfma_f32_16x16x32_bf16(a[ks], b, acc, 0, 0, 0);
            }
            int r = ct >> 3;
            int ch = (ct & 7) * 16 + (l & 15);
            #pragma unroll
            for (int reg = 0; reg < 4; ++reg) {
                int rn = ((l >> 4) << 2) + reg;
                qlds[rn * QSTRIDE + r * 136 + ch] = f2bf(acc[reg]);
            }
        }
    }
    __syncthreads();

    // phase B: wave w handles nodes n0 + w*4 .. +4
    #pragma unroll
    for (int q = 0; q < 4; ++q) {
        int tn = w * 4 + q;
        int ai[2] = {aiq[q][0], aiq[q][1]};
        int rv[2] = {rvq[q][0], rvq[q][1]};

        // write staged X rows (prefetched last iteration) into LDS.
        // edge=(l>>5)*16+((l>>1)&15): edge>>2 = l>>3, edge&3 = (l>>1)&3,
        // slot = ((l>>1)&3)^((l>>3)&3); ch base = (l&1)*8 + 16*i
        #pragma unroll
        for (int i = 0; i < 8; ++i)
            *(uint4v*)&xs[w][i * 512 + (l >> 3) * 64
                             + ((((l >> 1) & 3) ^ ((l >> 3) & 3))) * 16 + (l & 1) * 8] = sb[i];
        // prefetch next q's X rows (consumed next iteration; latency hides under compute)
        if (q < 3) {
            #pragma unroll
            for (int i = 0; i < 8; ++i)
                sb[i] = *(const uint4v*)&center_bf[(size_t)myrow[q + 1] * 128 + ((l & 1) + 2 * i) * 8];
        }

        // scores via MFMA: X(edges x 128) @ Q^T  (X from LDS staging)
        // A-frag: edge = t*16+(l&15) -> edge>>2 = 4t+((l>>2)&3), edge&3 = l&3,
        // slot = (l&3)^((l>>2)&3); ch = ks*32+(l>>4)*8+j -> ch>>4 = 2ks+(l>>5), ch&15 = ((l>>4)&1)*8+j
        float4v sc[2] = {};
        #pragma unroll
        for (int ks = 0; ks < 4; ++ks) {
            short8 qb = *(const short8*)&qlds[tn * QSTRIDE + (l & 7) * 136 + ks * 32 + ((l >> 4) << 3)];
            #pragma unroll
            for (int t = 0; t < 2; ++t) {
                short8 xa = *(const short8*)&xs[w][(2 * ks + (l >> 5)) * 512
                                  + (4 * t + ((l >> 2) & 3)) * 64
                                  + (((l & 3) ^ ((l >> 2) & 3))) * 16 + ((l >> 4) & 1) * 8];
                sc[t] = __builtin_amdgcn_mfma_f32_16x16x32_bf16(xa, qb, sc[t], 0, 0, 0);
            }
        }
        // select col rd per edge, mask, softmax (quad-uniform results)
        float sel[2][4];
        int ai2[2][4];
        #pragma unroll
        for (int t = 0; t < 2; ++t)
            #pragma unroll
            for (int reg = 0; reg < 4; ++reg) {
                int e2l = ((l >> 4) & 3) * 4 + reg;
                int rd2 = __shfl(rv[t], (l & 48) | e2l, 64);
                ai2[t][reg] = __shfl(ai[t], (l & 48) | e2l, 64);
                float s = __shfl(sc[t][reg], (l & 48) | rd2, 64);
                if (ai2[t][reg] == 0) s = 0.f;
                if (rd2 == 0) s = -1e9f;
                sel[t][reg] = s;
            }
        float mx = sel[0][0];
        #pragma unroll
        for (int t = 0; t < 2; ++t)
            #pragma unroll
            for (int reg = 0; reg < 4; ++reg) mx = fmaxf(mx, sel[t][reg]);
        mx = fmaxf(mx, __shfl_xor(mx, 16, 64));
        mx = fmaxf(mx, __shfl_xor(mx, 32, 64));
        float at[2][4];
        float sm = 0.f;
        #pragma unroll
        for (int t = 0; t < 2; ++t)
            #pragma unroll
            for (int reg = 0; reg < 4; ++reg) {
                at[t][reg] = __expf(sel[t][reg] - mx);
                sm += at[t][reg];
            }
        sm += __shfl_xor(sm, 16, 64);
        sm += __shfl_xor(sm, 32, 64);
        float inv = 1.0f / sm;
        #pragma unroll
        for (int t = 0; t < 2; ++t)
            #pragma unroll
            for (int reg = 0; reg < 4; ++reg) {
                at[t][reg] *= inv;
                if (ai2[t][reg] == 0) at[t][reg] = 0.f;   // pad rows contribute 0
            }

        // stage per-edge bf16(at) | rv<<16
        #pragma unroll
        for (int rg = 0; rg < 4; ++rg) {
            if (l == (l >> 4) * 20 + rg) {
                #pragma unroll
                for (int t = 0; t < 2; ++t)
                    edata[w][t * 16 + (l & 15)] = (unsigned)f2bf(at[t][rg]) | ((unsigned)rv[t] << 16);
            }
        }

        // bucket A-fragment: P[rel=l&15][edge k=(l>>4)*8+j]
        unsigned aw[4];
        #pragma unroll
        for (int jp = 0; jp < 4; ++jp) {
            unsigned m0 = edata[w][((l >> 4) << 3) + jp * 2];
            unsigned m1 = edata[w][((l >> 4) << 3) + jp * 2 + 1];
            unsigned s0 = ((m0 >> 16) == (unsigned)(l & 15)) ? (m0 & 0xFFFFu) : 0u;
            unsigned s1 = ((m1 >> 16) == (unsigned)(l & 15)) ? (m1 & 0xFFFFu) : 0u;
            aw[jp] = s0 | (s1 << 16);
        }
        uint4v av = {aw[0], aw[1], aw[2], aw[3]};
        short8 afrag = __builtin_bit_cast(short8, av);

        // bucket B-fragments from LDS staging (plain scalar gathers):
        //   lane l needs X[edge = (l>>4)*8 + jj][ch = ct*16 + (l&15)], jj = 0..7
        //   edge>>2 = (l>>4)*2 + (jj>>2); edge&3 = jj&3; slot = (jj&3)^((edge>>2)&3)
        #pragma unroll
        for (int ct = 0; ct < 8; ++ct) {
            unsigned short p[8];
            #pragma unroll
            for (int jj = 0; jj < 8; ++jj) {
                int st = (l >> 4) * 2 + (jj >> 2);
                int slot = (jj & 3) ^ (st & 3);
                p[jj] = xs[w][ct * 512 + st * 64 + slot * 16 + (l & 15)];
            }
            uint4v bv = {(unsigned)p[0] | ((unsigned)p[1] << 16),
                         (unsigned)p[2] | ((unsigned)p[3] << 16),
                         (unsigned)p[4] | ((unsigned)p[5] << 16),
                         (unsigned)p[6] | ((unsigned)p[7] << 16)};
            float4v zc = {};
            float4v acc = __builtin_amdgcn_mfma_f32_16x16x32_bf16(
                afrag, __builtin_bit_cast(short8, bv), zc, 0, 0, 0);
            if (l < 32) {     // C rows 0..7 = relations; rows 8..15 are zero
                int rbase = (l >> 4) << 2;
                #pragma unroll
                for (int reg = 0; reg < 4; ++reg)
                    qlds[tn * QSTRIDE + (rbase + reg) * 136 + ct * 16 + (l & 15)] = f2bf(acc[reg]);
            }
        }
    }
    __syncthreads();

    // phase C: agg16x128 = bucket(16x1024, r-stride 136) @ RVF(1024x128), fused epilogue
    #pragma unroll
    for (int ci = 0; ci < 2; ++ci) {
        int ct = w * 2 + ci;
        float4v acc = {};
        #pragma unroll 4
        for (int ks = 0; ks < 32; ++ks) {
            short8 a = *(const short8*)&qlds[(l & 15) * QSTRIDE + (ks >> 2) * 136
                                             + (ks & 3) * 32 + ((l >> 4) << 3)];
            short8 b = *(const short8*)&RVFfrag[(((ks * 8 + ct) << 6) + l) * 8];
            acc = __builtin_amdgcn_mfma_f32_16x16x32_bf16(a, b, acc, 0, 0, 0);
        }
        int col = ct * 16 + (l & 15);
        float bb = fcb[col];
        #pragma unroll
        for (int reg = 0; reg < 4; ++reg) {
            int n = n0 + ((l >> 4) << 2) + reg;
            float v = acc[reg] + bb;
            v = v > 0.f ? v : 0.f;
            out[(size_t)n * 128 + col] = bf2f(center_bf[(size_t)n * 128 + col]) + v;
        }
    }
}

extern "C" void kernel_launch(void* const* d_in, const int* in_sizes, int n_in,
                              void* d_out, int out_size, void* d_ws, size_t ws_size,
                              hipStream_t stream) {
    const float* node_state = (const float*)d_in[0];
    const int*   adjacency  = (const int*)d_in[1];
    const int*   point_enc  = (const int*)d_in[2];
    const int*   relation   = (const int*)d_in[3];
    const float* pew        = (const float*)d_in[4];
    const float* relw       = (const float*)d_in[5];
    const float* qw         = (const float*)d_in[6];
    const float* kw         = (const float*)d_in[7];
    const float* vw         = (const float*)d_in[8];
    const float* fcw        = (const float*)d_in[9];
    const float* fcb        = (const float*)d_in[10];
    float* out = (float*)d_out;

    char* ws = (char*)d_ws;
    unsigned short* BallQfrag = (unsigned short*)ws;  ws += 128 * 1024 * 2;            // 256 KB
    unsigned short* RVFfrag   = (unsigned short*)ws;  ws += 1024 * 128 * 2;            // 256 KB
    unsigned short* center_bf = (unsigned short*)ws;  ws += (size_t)NNODE * 128 * 2;   // 4 MB
    unsigned short* pewfrag   = (unsigned short*)ws;  ws += 8 * 32768 * 2;             // 512 KB
    int* blockhist            = (int*)ws;             ws += 64 * 8 * 4;
    int* cnt                  = (int*)ws;             ws += 32;
    int* basep                = (int*)ws;             ws += 32;
    int* list                 = (int*)ws;             ws += NNODE * 4;                 // 64 KB

    k_setup<<<1152, 256, 0, stream>>>(pew, qw, kw, relw, vw, fcw, point_enc,
                                      pewfrag, BallQfrag, RVFfrag, blockhist);
    k_scatter<<<64, 256, 0, stream>>>(point_enc, blockhist, list, cnt, basep);
    k_center<<<dim3(192, 8), 256, 0, stream>>>(node_state, pewfrag, list, cnt, basep, center_bf);
    k_final<<<NNODE / 16, 256, 0, stream>>>(center_bf, BallQfrag, RVFfrag,
                                            adjacency, relation, fcb, out);
}